// Round 5
// baseline (1414.316 us; speedup 1.0000x reference)
//
#include <hip/hip_runtime.h>
#include <hip/hip_bf16.h>

#define N_NODES 50000
#define N_EDGES 1600000
#define N_CAND  1000
#define N_GRAPHS 50
#define EMB 32
#define L_LAYERS 4

#define BSH 5
#define BNODES 32
#define NBK ((N_NODES + BNODES - 1) >> BSH)   // 1563 buckets of 32 nodes
#define STILE 4096
#define NBLK_S ((N_EDGES + STILE - 1) / STILE) // 391

#define W1A_OFF 0
#define W1B_OFF 4096
#define W2_OFF  8192
#define WE_OFF  12288
#define C1_OFF  12416
#define C2_OFF  12544
#define H_OFF   12800
#define NODE_F  (N_NODES * EMB)

#define BH_OFF    (H_OFF + 4 * NODE_F)                 // int[NBK]   bucket hist
#define BOFF_OFF  (BH_OFF + NBK)                       // int[NBK+1] bucket offsets
#define BCUR_OFF  (BOFF_OFF + NBK + 1)                 // int[NBK]   bucket cursors
#define CSR_OFF   (((BCUR_OFF + NBK) + 1) & ~1)        // int2[N_EDGES] bucket-ordered edges

typedef float f32x4 __attribute__((ext_vector_type(4)));
typedef __bf16 bf16x8 __attribute__((ext_vector_type(8)));
union BF8 { unsigned short us[8]; bf16x8 v; };

static __device__ __forceinline__ unsigned short f2bf(float f) {
    unsigned u = __builtin_bit_cast(unsigned, f);
    u += 0x7FFFu + ((u >> 16) & 1u);   // round-to-nearest-even
    return (unsigned short)(u >> 16);
}

__global__ void prep_k(const float* __restrict__ W1, const float* __restrict__ b1,
                       const float* __restrict__ g1, const float* __restrict__ be1,
                       const float* __restrict__ m1, const float* __restrict__ v1,
                       const float* __restrict__ W2, const float* __restrict__ b2,
                       const float* __restrict__ g2, const float* __restrict__ be2,
                       const float* __restrict__ m2, const float* __restrict__ v2,
                       float* __restrict__ ws) {
    int t = threadIdx.x;  // 256 threads, 1 block
    for (int l = 0; l < L_LAYERS; ++l) {
        for (int i = t; i < 1024; i += 256) {
            int k = i >> 5, j = i & 31;
            float s1 = g1[l * 32 + j] * rsqrtf(v1[l * 32 + j] + 1e-5f);
            float s2 = g2[l * 32 + j] * rsqrtf(v2[l * 32 + j] + 1e-5f);
            ws[W1A_OFF + l * 1024 + i] = W1[(l * 65 + k) * 32 + j] * s1;
            ws[W1B_OFF + l * 1024 + i] = W1[(l * 65 + 32 + k) * 32 + j] * s1;
            ws[W2_OFF  + l * 1024 + i] = W2[(l * 32 + k) * 32 + j] * s2;
            if (k == 0) {
                ws[WE_OFF + l * 32 + j] = W1[(l * 65 + 64) * 32 + j] * s1;
                ws[C1_OFF + l * 32 + j] = b1[l * 32 + j] * s1 + be1[l * 32 + j] - m1[l * 32 + j] * s1;
                ws[C2_OFF + l * 32 + j] = b2[l * 32 + j] * s2 + be2[l * 32 + j] - m2[l * 32 + j] * s2;
            }
        }
    }
}

__global__ void embed_k(const float* __restrict__ x, const float* __restrict__ Win,
                        const float* __restrict__ bin, float* __restrict__ h) {
    int t = blockIdx.x * blockDim.x + threadIdx.x;
    if (t >= NODE_F) return;
    int n = t >> 5, j = t & 31;
    h[t] = x[2 * n] * Win[j] + x[2 * n + 1] * Win[32 + j] + bin[j];
}

__global__ void zero_k(int* __restrict__ p, int n) {
    int t = blockIdx.x * blockDim.x + threadIdx.x;
    if (t < n) p[t] = 0;
}

// per-block LDS histogram of dst>>BSH, one global atomic per bucket per block
__global__ void bhist_k(const int* __restrict__ ei, int* __restrict__ bh) {
    __shared__ int lh[NBK];
    for (int i = threadIdx.x; i < NBK; i += 256) lh[i] = 0;
    __syncthreads();
    int tb = blockIdx.x * STILE;
#pragma unroll
    for (int i = 0; i < STILE / 256; ++i) {
        int e = tb + i * 256 + threadIdx.x;
        if (e < N_EDGES) atomicAdd(&lh[ei[N_EDGES + e] >> BSH], 1);
    }
    __syncthreads();
    for (int i = threadIdx.x; i < NBK; i += 256)
        if (lh[i]) atomicAdd(&bh[i], lh[i]);
}

// single block: exclusive scan of bh[NBK] -> boffs, bcur
__global__ void bscan_k(const int* __restrict__ bh, int* __restrict__ boffs,
                        int* __restrict__ bcur) {
    __shared__ int part[1024];
    const int CH = (NBK + 1023) / 1024;  // 2
    int t = threadIdx.x;
    int base = t * CH;
    int s = 0;
    for (int i = 0; i < CH; ++i) {
        int idx = base + i;
        if (idx < NBK) s += bh[idx];
    }
    part[t] = s;
    __syncthreads();
    for (int d = 1; d < 1024; d <<= 1) {
        int v = (t >= d) ? part[t - d] : 0;
        __syncthreads();
        part[t] += v;
        __syncthreads();
    }
    int run = part[t] - s;
    for (int i = 0; i < CH; ++i) {
        int idx = base + i;
        if (idx < NBK) {
            boffs[idx] = run;
            bcur[idx] = run;
            run += bh[idx];
        }
    }
    if (t == 1023) boffs[NBK] = N_EDGES;
}

// block-aggregated binning: LDS hist -> one global reserve per bucket -> direct write
__global__ void bscatter_k(const int* __restrict__ ei, const float* __restrict__ ea,
                           int* __restrict__ bcur, int2* __restrict__ csr) {
    __shared__ int lofs[NBK];
    for (int i = threadIdx.x; i < NBK; i += 256) lofs[i] = 0;
    __syncthreads();
    int tb = blockIdx.x * STILE;
#pragma unroll
    for (int i = 0; i < STILE / 256; ++i) {
        int e = tb + i * 256 + threadIdx.x;
        if (e < N_EDGES) atomicAdd(&lofs[ei[N_EDGES + e] >> BSH], 1);
    }
    __syncthreads();
    for (int bk = threadIdx.x; bk < NBK; bk += 256) {
        int c = lofs[bk];
        lofs[bk] = c ? atomicAdd(&bcur[bk], c) : 0;
    }
    __syncthreads();
#pragma unroll
    for (int i = 0; i < STILE / 256; ++i) {
        int e = tb + i * 256 + threadIdx.x;
        if (e < N_EDGES) {
            int src = ei[e], dst = ei[N_EDGES + e];
            int bk = dst >> BSH;
            int pos = atomicAdd(&lofs[bk], 1);
            int2 p;
            p.x = src | ((dst & (BNODES - 1)) << 16);
            p.y = __float_as_int(ea[e]);
            csr[pos] = p;
        }
    }
}

// ---------------- per-layer kernels ----------------
__global__ void node_k(const float* __restrict__ h, const float* __restrict__ ws, int l,
                       float* __restrict__ hA, float* __restrict__ hB) {
    __shared__ float sA[1024], sB[1024];
    const float* W1A = ws + W1A_OFF + l * 1024;
    const float* W1B = ws + W1B_OFF + l * 1024;
    for (int i = threadIdx.x; i < 1024; i += blockDim.x) { sA[i] = W1A[i]; sB[i] = W1B[i]; }
    __syncthreads();
    int t = blockIdx.x * blockDim.x + threadIdx.x;
    if (t >= NODE_F) return;
    int j = t & 31;
    float hv = h[t];
    float a = ws[C1_OFF + l * 32 + j];
    float b = 0.f;
#pragma unroll
    for (int k = 0; k < 32; ++k) {
        float hk = __shfl(hv, k, 32);
        a += hk * sA[k * 32 + j];
        b += hk * sB[k * 32 + j];
    }
    hA[t] = a;
    hB[t] = b;
}

// bucket-centric: one block per 32-node bucket; LDS acc init = h (residual folded);
// waves consume bucket edges in 16-edge chunks, MFMA per chunk, ds_add_f32 accumulate.
// A frag: lane l = row l&15, k = 8*(l>>4)+i. C/D: col=lane&15, row=4*(lane>>4)+reg.
__launch_bounds__(256)
__global__ void edge_bucket_k(const int* __restrict__ boffs, const int2* __restrict__ csr,
                              const float* __restrict__ ws, int l,
                              const float* __restrict__ h, const float* __restrict__ hA,
                              const float* __restrict__ hB, float* __restrict__ hnext) {
    __shared__ float acc[BNODES * EMB];   // 4 KB
    const int b = blockIdx.x;
    const int nbase = b << BSH;
    const int t = threadIdx.x;
    for (int i = t; i < BNODES * EMB; i += 256) {
        int n = nbase + (i >> 5);
        acc[i] = (n < N_NODES) ? h[n * 32 + (i & 31)] : 0.f;
    }
    const int lane = t & 63;
    const int wave = t >> 6;
    const int r = lane & 15;   // edge slot in chunk / D col
    const int q = lane >> 4;   // channel octet

    const float* W2p = ws + W2_OFF + l * 1024;
    BF8 bf0, bf1;
#pragma unroll
    for (int i = 0; i < 8; ++i) {
        bf0.us[i] = f2bf(W2p[(8 * q + i) * 32 + r]);
        bf1.us[i] = f2bf(W2p[(8 * q + i) * 32 + 16 + r]);
    }
    const float c2a = ws[C2_OFF + l * 32 + r];
    const float c2b = ws[C2_OFF + l * 32 + 16 + r];
    const f32x4 we0 = *(const f32x4*)(ws + WE_OFF + l * 32 + 8 * q);
    const f32x4 we1 = *(const f32x4*)(ws + WE_OFF + l * 32 + 8 * q + 4);
    __syncthreads();

    const int beg = boffs[b], end = boffs[b + 1];
    for (int ebase = beg + wave * 16; ebase < end; ebase += 64) {
        int e = ebase + r;
        if (e >= end) e = end - 1;
        int2 p = csr[e];
        int src  = p.x & 0xFFFF;
        int dloc = (p.x >> 16) & (BNODES - 1);
        float eav = __int_as_float(p.y);
        const f32x4 hb0 = *(const f32x4*)(hB + src * 32 + 8 * q);
        const f32x4 hb1 = *(const f32x4*)(hB + src * 32 + 8 * q + 4);
        const f32x4 ha0 = *(const f32x4*)(hA + (nbase + dloc) * 32 + 8 * q);
        const f32x4 ha1 = *(const f32x4*)(hA + (nbase + dloc) * 32 + 8 * q + 4);
        BF8 a;
#pragma unroll
        for (int i = 0; i < 4; ++i) {
            a.us[i]     = f2bf(fmaxf(ha0[i] + hb0[i] + eav * we0[i], 0.f));
            a.us[i + 4] = f2bf(fmaxf(ha1[i] + hb1[i] + eav * we1[i], 0.f));
        }
        f32x4 z = {0.f, 0.f, 0.f, 0.f};
        f32x4 d0 = __builtin_amdgcn_mfma_f32_16x16x32_bf16(a.v, bf0.v, z, 0, 0, 0);
        f32x4 d1 = __builtin_amdgcn_mfma_f32_16x16x32_bf16(a.v, bf1.v, z, 0, 0, 0);
        int nreal = end - ebase;
#pragma unroll
        for (int reg = 0; reg < 4; ++reg) {
            int row = 4 * q + reg;
            int drow = __shfl(dloc, row, 16);
            if (row < nreal) {
                atomicAdd(&acc[drow * 32 + r],      fmaxf(d0[reg] + c2a, 0.f));
                atomicAdd(&acc[drow * 32 + 16 + r], fmaxf(d1[reg] + c2b, 0.f));
            }
        }
    }
    __syncthreads();
    for (int i = t; i < BNODES * EMB; i += 256) {
        int n = nbase + (i >> 5);
        if (n < N_NODES) hnext[n * 32 + (i & 31)] = acc[i];
    }
}

__global__ void head_k(const float* __restrict__ h, const int* __restrict__ cand,
                       const int* __restrict__ batch, const float* __restrict__ Wout,
                       const float* __restrict__ bout, float* __restrict__ out) {
    __shared__ float Lg[N_CAND];
    __shared__ int Sg[N_CAND];
    __shared__ float gm[N_GRAPHS], gs[N_GRAPHS];
    int t = threadIdx.x;  // 1024
    if (t < N_CAND) {
        int c = cand[t];
        float acc = bout[0];
#pragma unroll
        for (int j = 0; j < 32; ++j) acc += h[c * 32 + j] * Wout[j];
        Lg[t] = acc;
        Sg[t] = batch[c];
    }
    __syncthreads();
    if (t < 16 * N_GRAPHS) {
        int g = t >> 4, s = t & 15;
        float m = -1e30f;
        for (int i = s; i < N_CAND; i += 16)
            if (Sg[i] == g) m = fmaxf(m, Lg[i]);
#pragma unroll
        for (int d = 1; d < 16; d <<= 1) m = fmaxf(m, __shfl_xor(m, d, 64));
        float ssum = 0.f;
        for (int i = s; i < N_CAND; i += 16)
            if (Sg[i] == g) ssum += expf(Lg[i] - m);
#pragma unroll
        for (int d = 1; d < 16; d <<= 1) ssum += __shfl_xor(ssum, d, 64);
        if (s == 0) { gm[g] = m; gs[g] = logf(ssum); }
    }
    __syncthreads();
    if (t < N_CAND) out[t] = Lg[t] - gm[Sg[t]] - gs[Sg[t]];
}

extern "C" void kernel_launch(void* const* d_in, const int* in_sizes, int n_in,
                              void* d_out, int out_size, void* d_ws, size_t ws_size,
                              hipStream_t stream) {
    const float* x    = (const float*)d_in[0];
    const int*   ei   = (const int*)d_in[1];
    const float* eatt = (const float*)d_in[2];
    const int*   cand = (const int*)d_in[3];
    const int*   batch= (const int*)d_in[4];
    const float* Win  = (const float*)d_in[5];
    const float* bin  = (const float*)d_in[6];
    const float* W1   = (const float*)d_in[7];
    const float* b1   = (const float*)d_in[8];
    const float* g1   = (const float*)d_in[9];
    const float* be1  = (const float*)d_in[10];
    const float* m1   = (const float*)d_in[11];
    const float* v1   = (const float*)d_in[12];
    const float* W2   = (const float*)d_in[13];
    const float* b2   = (const float*)d_in[14];
    const float* g2   = (const float*)d_in[15];
    const float* be2  = (const float*)d_in[16];
    const float* m2   = (const float*)d_in[17];
    const float* v2   = (const float*)d_in[18];
    const float* Wout = (const float*)d_in[19];
    const float* bout = (const float*)d_in[20];
    float* out = (float*)d_out;
    float* ws = (float*)d_ws;

    float* h0 = ws + H_OFF;
    float* h1 = ws + H_OFF + NODE_F;
    float* hA = ws + H_OFF + 2 * NODE_F;
    float* hB = ws + H_OFF + 3 * NODE_F;
    int* bh    = (int*)(ws + BH_OFF);
    int* boffs = (int*)(ws + BOFF_OFF);
    int* bcur  = (int*)(ws + BCUR_OFF);
    int2* csr  = (int2*)(ws + CSR_OFF);

    prep_k<<<1, 256, 0, stream>>>(W1, b1, g1, be1, m1, v1, W2, b2, g2, be2, m2, v2, ws);
    embed_k<<<(NODE_F + 255) / 256, 256, 0, stream>>>(x, Win, bin, h0);

    zero_k<<<(NBK + 255) / 256, 256, 0, stream>>>(bh, NBK);
    bhist_k<<<NBLK_S, 256, 0, stream>>>(ei, bh);
    bscan_k<<<1, 1024, 0, stream>>>(bh, boffs, bcur);
    bscatter_k<<<NBLK_S, 256, 0, stream>>>(ei, eatt, bcur, csr);

    float* cur = h0;
    float* nxt = h1;
    for (int l = 0; l < L_LAYERS; ++l) {
        node_k<<<(NODE_F + 255) / 256, 256, 0, stream>>>(cur, ws, l, hA, hB);
        edge_bucket_k<<<NBK, 256, 0, stream>>>(boffs, csr, ws, l, cur, hA, hB, nxt);
        float* tmp = cur; cur = nxt; nxt = tmp;
    }

    head_k<<<1, 1024, 0, stream>>>(cur, cand, batch, Wout, bout, out);
}

// Round 6
// 389.251 us; speedup vs baseline: 3.6334x; 3.6334x over previous
//
#include <hip/hip_runtime.h>
#include <hip/hip_bf16.h>

#define N_NODES 50000
#define N_EDGES 1600000
#define N_CAND  1000
#define N_GRAPHS 50
#define EMB 32
#define L_LAYERS 4

#define BSH 5
#define BNODES 32
#define NBK ((N_NODES + BNODES - 1) >> BSH)    // 1563 buckets of 32 nodes
#define STILE 4096
#define NBLK_S ((N_EDGES + STILE - 1) / STILE) // 391

#define W1A_OFF 0
#define W1B_OFF 4096
#define W2_OFF  8192
#define WE_OFF  12288
#define C1_OFF  12416
#define C2_OFF  12544
#define H_OFF   12800
#define NODE_F  (N_NODES * EMB)

#define BH_OFF    (H_OFF + 4 * NODE_F)                   // int[NBK]
#define BOFF_OFF  (BH_OFF + NBK)                         // int[NBK+1]
#define BCUR_OFF  (BOFF_OFF + NBK + 1)                   // int[NBK]
#define OFFS_OFF  (BCUR_OFF + NBK)                       // int[N_NODES+1]
#define CSR_OFF   (((OFFS_OFF + N_NODES + 1) + 1) & ~1)  // int2[N_EDGES] node-ordered
// csr_stage (int2[N_EDGES] = 12.8MB) aliases hA/hB region (used before node_k runs)

typedef float f32x4 __attribute__((ext_vector_type(4)));
typedef __bf16 bf16x8 __attribute__((ext_vector_type(8)));
union BF8 { unsigned short us[8]; bf16x8 v; };

static __device__ __forceinline__ unsigned short f2bf(float f) {
    unsigned u = __builtin_bit_cast(unsigned, f);
    u += 0x7FFFu + ((u >> 16) & 1u);   // round-to-nearest-even
    return (unsigned short)(u >> 16);
}

__global__ void prep_k(const float* __restrict__ W1, const float* __restrict__ b1,
                       const float* __restrict__ g1, const float* __restrict__ be1,
                       const float* __restrict__ m1, const float* __restrict__ v1,
                       const float* __restrict__ W2, const float* __restrict__ b2,
                       const float* __restrict__ g2, const float* __restrict__ be2,
                       const float* __restrict__ m2, const float* __restrict__ v2,
                       float* __restrict__ ws) {
    int t = threadIdx.x;  // 256 threads, 1 block
    for (int l = 0; l < L_LAYERS; ++l) {
        for (int i = t; i < 1024; i += 256) {
            int k = i >> 5, j = i & 31;
            float s1 = g1[l * 32 + j] * rsqrtf(v1[l * 32 + j] + 1e-5f);
            float s2 = g2[l * 32 + j] * rsqrtf(v2[l * 32 + j] + 1e-5f);
            ws[W1A_OFF + l * 1024 + i] = W1[(l * 65 + k) * 32 + j] * s1;
            ws[W1B_OFF + l * 1024 + i] = W1[(l * 65 + 32 + k) * 32 + j] * s1;
            ws[W2_OFF  + l * 1024 + i] = W2[(l * 32 + k) * 32 + j] * s2;
            if (k == 0) {
                ws[WE_OFF + l * 32 + j] = W1[(l * 65 + 64) * 32 + j] * s1;
                ws[C1_OFF + l * 32 + j] = b1[l * 32 + j] * s1 + be1[l * 32 + j] - m1[l * 32 + j] * s1;
                ws[C2_OFF + l * 32 + j] = b2[l * 32 + j] * s2 + be2[l * 32 + j] - m2[l * 32 + j] * s2;
            }
        }
    }
}

__global__ void embed_k(const float* __restrict__ x, const float* __restrict__ Win,
                        const float* __restrict__ bin, float* __restrict__ h) {
    int t = blockIdx.x * blockDim.x + threadIdx.x;
    if (t >= NODE_F) return;
    int n = t >> 5, j = t & 31;
    h[t] = x[2 * n] * Win[j] + x[2 * n + 1] * Win[32 + j] + bin[j];
}

__global__ void zero_k(int* __restrict__ p, int n) {
    int t = blockIdx.x * blockDim.x + threadIdx.x;
    if (t < n) p[t] = 0;
}

// per-block LDS histogram of dst>>BSH, one global atomic per bucket per block
__global__ void bhist_k(const int* __restrict__ ei, int* __restrict__ bh) {
    __shared__ int lh[NBK];
    for (int i = threadIdx.x; i < NBK; i += 256) lh[i] = 0;
    __syncthreads();
    int tb = blockIdx.x * STILE;
#pragma unroll
    for (int i = 0; i < STILE / 256; ++i) {
        int e = tb + i * 256 + threadIdx.x;
        if (e < N_EDGES) atomicAdd(&lh[ei[N_EDGES + e] >> BSH], 1);
    }
    __syncthreads();
    for (int i = threadIdx.x; i < NBK; i += 256)
        if (lh[i]) atomicAdd(&bh[i], lh[i]);
}

// single block: exclusive scan of bh[NBK] -> boffs, bcur
__global__ void bscan_k(const int* __restrict__ bh, int* __restrict__ boffs,
                        int* __restrict__ bcur) {
    __shared__ int part[1024];
    const int CH = (NBK + 1023) / 1024;  // 2
    int t = threadIdx.x;
    int base = t * CH;
    int s = 0;
    for (int i = 0; i < CH; ++i) {
        int idx = base + i;
        if (idx < NBK) s += bh[idx];
    }
    part[t] = s;
    __syncthreads();
    for (int d = 1; d < 1024; d <<= 1) {
        int v = (t >= d) ? part[t - d] : 0;
        __syncthreads();
        part[t] += v;
        __syncthreads();
    }
    int run = part[t] - s;
    for (int i = 0; i < CH; ++i) {
        int idx = base + i;
        if (idx < NBK) {
            boffs[idx] = run;
            bcur[idx] = run;
            run += bh[idx];
        }
    }
    if (t == 1023) boffs[NBK] = N_EDGES;
}

// block-aggregated binning: LDS hist -> one global reserve per bucket -> direct write
__global__ void bscatter_k(const int* __restrict__ ei, const float* __restrict__ ea,
                           int* __restrict__ bcur, int2* __restrict__ stage) {
    __shared__ int lofs[NBK];
    for (int i = threadIdx.x; i < NBK; i += 256) lofs[i] = 0;
    __syncthreads();
    int tb = blockIdx.x * STILE;
#pragma unroll
    for (int i = 0; i < STILE / 256; ++i) {
        int e = tb + i * 256 + threadIdx.x;
        if (e < N_EDGES) atomicAdd(&lofs[ei[N_EDGES + e] >> BSH], 1);
    }
    __syncthreads();
    for (int bk = threadIdx.x; bk < NBK; bk += 256) {
        int c = lofs[bk];
        lofs[bk] = c ? atomicAdd(&bcur[bk], c) : 0;
    }
    __syncthreads();
#pragma unroll
    for (int i = 0; i < STILE / 256; ++i) {
        int e = tb + i * 256 + threadIdx.x;
        if (e < N_EDGES) {
            int src = ei[e], dst = ei[N_EDGES + e];
            int bk = dst >> BSH;
            int pos = atomicAdd(&lofs[bk], 1);
            int2 p;
            p.x = src | ((dst & (BNODES - 1)) << 16);
            p.y = __float_as_int(ea[e]);
            stage[pos] = p;
        }
    }
}

// one block per bucket: 32-entry hist+prefix -> offs[n]; scatter to exact node order.
// All writes land in the bucket's own contiguous window (single L2 writeback).
__global__ void bsort2_k(const int* __restrict__ boffs, const int2* __restrict__ stage,
                         int* __restrict__ offs, int2* __restrict__ csr) {
    __shared__ int cnt[BNODES];
    __shared__ int pre[BNODES + 1];
    const int b = blockIdx.x;
    const int nbase = b << BSH;
    const int t = threadIdx.x;
    const int beg = boffs[b], end = boffs[b + 1];
    if (t < BNODES) cnt[t] = 0;
    __syncthreads();
    for (int i = beg + t; i < end; i += 256)
        atomicAdd(&cnt[(stage[i].x >> 16) & (BNODES - 1)], 1);
    __syncthreads();
    if (t == 0) {
        int run = 0;
        for (int i = 0; i < BNODES; ++i) { pre[i] = run; run += cnt[i]; }
        pre[BNODES] = run;
    }
    __syncthreads();
    if (t < BNODES) {
        cnt[t] = pre[t];  // reuse as local cursor
        int n = nbase + t;
        if (n < N_NODES) offs[n] = beg + pre[t];
    }
    if (b == NBK - 1 && t == 0) offs[N_NODES] = N_EDGES;
    __syncthreads();
    for (int i = beg + t; i < end; i += 256) {
        int2 p = stage[i];
        int dloc = (p.x >> 16) & (BNODES - 1);
        int pos = beg + atomicAdd(&cnt[dloc], 1);
        int2 q; q.x = p.x & 0xFFFF; q.y = p.y;
        csr[pos] = q;
    }
}

// ---------------- per-layer kernels ----------------
__global__ void node_k(const float* __restrict__ h, const float* __restrict__ ws, int l,
                       float* __restrict__ hA, float* __restrict__ hB) {
    __shared__ float sA[1024], sB[1024];
    const float* W1A = ws + W1A_OFF + l * 1024;
    const float* W1B = ws + W1B_OFF + l * 1024;
    for (int i = threadIdx.x; i < 1024; i += blockDim.x) { sA[i] = W1A[i]; sB[i] = W1B[i]; }
    __syncthreads();
    int t = blockIdx.x * blockDim.x + threadIdx.x;
    if (t >= NODE_F) return;
    int j = t & 31;
    float hv = h[t];
    float a = ws[C1_OFF + l * 32 + j];
    float b = 0.f;
#pragma unroll
    for (int k = 0; k < 32; ++k) {
        float hk = __shfl(hv, k, 32);
        a += hk * sA[k * 32 + j];
        b += hk * sB[k * 32 + j];
    }
    hA[t] = a;
    hB[t] = b;
}

// One wave per node; 32 edges per iteration (2 A-frags, 4 MFMAs) for gather ILP.
// A frag: lane l = row l&15, k = 8*(l>>4)+i. C/D: col=lane&15, row=4*(lane>>4)+reg.
__launch_bounds__(256)
__global__ void edge_mfma_k(const int* __restrict__ offs, const int2* __restrict__ csr,
                            const float* __restrict__ ws, int l,
                            const float* __restrict__ h, const float* __restrict__ hA,
                            const float* __restrict__ hB, float* __restrict__ hnext) {
    const int lane = threadIdx.x & 63;
    const int n = blockIdx.x * 4 + (threadIdx.x >> 6);
    if (n >= N_NODES) return;
    const int r = lane & 15;   // A row / D col
    const int q = lane >> 4;   // channel octet

    const float* W2p = ws + W2_OFF + l * 1024;
    BF8 b0, b1;
#pragma unroll
    for (int i = 0; i < 8; ++i) {
        b0.us[i] = f2bf(W2p[(8 * q + i) * 32 + r]);
        b1.us[i] = f2bf(W2p[(8 * q + i) * 32 + 16 + r]);
    }
    const float c2a = ws[C2_OFF + l * 32 + r];
    const float c2b = ws[C2_OFF + l * 32 + 16 + r];
    const f32x4 hA0 = *(const f32x4*)(hA + n * 32 + 8 * q);
    const f32x4 hA1 = *(const f32x4*)(hA + n * 32 + 8 * q + 4);
    const f32x4 we0 = *(const f32x4*)(ws + WE_OFF + l * 32 + 8 * q);
    const f32x4 we1 = *(const f32x4*)(ws + WE_OFF + l * 32 + 8 * q + 4);

    const int beg = offs[n], end = offs[n + 1];
    float ns0 = 0.f, ns1 = 0.f;

    for (int ebase = beg; ebase < end; ebase += 32) {
        const int last = end - 1;
        int e0 = ebase + r;       e0 = (e0 < last) ? e0 : last;
        int e1 = ebase + 16 + r;  e1 = (e1 < last) ? e1 : last;
        int2 p0 = csr[e0];
        int2 p1 = csr[e1];
        int s0 = p0.x; float ea0 = __int_as_float(p0.y);
        int s1 = p1.x; float ea1 = __int_as_float(p1.y);
        const f32x4 hb00 = *(const f32x4*)(hB + s0 * 32 + 8 * q);
        const f32x4 hb01 = *(const f32x4*)(hB + s0 * 32 + 8 * q + 4);
        const f32x4 hb10 = *(const f32x4*)(hB + s1 * 32 + 8 * q);
        const f32x4 hb11 = *(const f32x4*)(hB + s1 * 32 + 8 * q + 4);
        BF8 a0, a1;
#pragma unroll
        for (int i = 0; i < 4; ++i) {
            a0.us[i]     = f2bf(fmaxf(hA0[i] + hb00[i] + ea0 * we0[i], 0.f));
            a0.us[i + 4] = f2bf(fmaxf(hA1[i] + hb01[i] + ea0 * we1[i], 0.f));
            a1.us[i]     = f2bf(fmaxf(hA0[i] + hb10[i] + ea1 * we0[i], 0.f));
            a1.us[i + 4] = f2bf(fmaxf(hA1[i] + hb11[i] + ea1 * we1[i], 0.f));
        }
        f32x4 z = {0.f, 0.f, 0.f, 0.f};
        f32x4 acc00 = __builtin_amdgcn_mfma_f32_16x16x32_bf16(a0.v, b0.v, z, 0, 0, 0);
        f32x4 acc01 = __builtin_amdgcn_mfma_f32_16x16x32_bf16(a0.v, b1.v, z, 0, 0, 0);
        f32x4 acc10 = __builtin_amdgcn_mfma_f32_16x16x32_bf16(a1.v, b0.v, z, 0, 0, 0);
        f32x4 acc11 = __builtin_amdgcn_mfma_f32_16x16x32_bf16(a1.v, b1.v, z, 0, 0, 0);
        int nreal = end - ebase;
#pragma unroll
        for (int reg = 0; reg < 4; ++reg) {
            int row = 4 * q + reg;
            ns0 += (row < nreal) ? fmaxf(acc00[reg] + c2a, 0.f) : 0.f;
            ns1 += (row < nreal) ? fmaxf(acc01[reg] + c2b, 0.f) : 0.f;
            ns0 += (row + 16 < nreal) ? fmaxf(acc10[reg] + c2a, 0.f) : 0.f;
            ns1 += (row + 16 < nreal) ? fmaxf(acc11[reg] + c2b, 0.f) : 0.f;
        }
    }
    ns0 += __shfl_xor(ns0, 16, 64);
    ns0 += __shfl_xor(ns0, 32, 64);
    ns1 += __shfl_xor(ns1, 16, 64);
    ns1 += __shfl_xor(ns1, 32, 64);
    if (lane < 32) {
        float base = h[n * 32 + lane];
        hnext[n * 32 + lane] = base + ((lane & 16) ? ns1 : ns0);
    }
}

__global__ void head_k(const float* __restrict__ h, const int* __restrict__ cand,
                       const int* __restrict__ batch, const float* __restrict__ Wout,
                       const float* __restrict__ bout, float* __restrict__ out) {
    __shared__ float Lg[N_CAND];
    __shared__ int Sg[N_CAND];
    __shared__ float gm[N_GRAPHS], gs[N_GRAPHS];
    int t = threadIdx.x;  // 1024
    if (t < N_CAND) {
        int c = cand[t];
        float acc = bout[0];
#pragma unroll
        for (int j = 0; j < 32; ++j) acc += h[c * 32 + j] * Wout[j];
        Lg[t] = acc;
        Sg[t] = batch[c];
    }
    __syncthreads();
    if (t < 16 * N_GRAPHS) {
        int g = t >> 4, s = t & 15;
        float m = -1e30f;
        for (int i = s; i < N_CAND; i += 16)
            if (Sg[i] == g) m = fmaxf(m, Lg[i]);
#pragma unroll
        for (int d = 1; d < 16; d <<= 1) m = fmaxf(m, __shfl_xor(m, d, 64));
        float ssum = 0.f;
        for (int i = s; i < N_CAND; i += 16)
            if (Sg[i] == g) ssum += expf(Lg[i] - m);
#pragma unroll
        for (int d = 1; d < 16; d <<= 1) ssum += __shfl_xor(ssum, d, 64);
        if (s == 0) { gm[g] = m; gs[g] = logf(ssum); }
    }
    __syncthreads();
    if (t < N_CAND) out[t] = Lg[t] - gm[Sg[t]] - gs[Sg[t]];
}

extern "C" void kernel_launch(void* const* d_in, const int* in_sizes, int n_in,
                              void* d_out, int out_size, void* d_ws, size_t ws_size,
                              hipStream_t stream) {
    const float* x    = (const float*)d_in[0];
    const int*   ei   = (const int*)d_in[1];
    const float* eatt = (const float*)d_in[2];
    const int*   cand = (const int*)d_in[3];
    const int*   batch= (const int*)d_in[4];
    const float* Win  = (const float*)d_in[5];
    const float* bin  = (const float*)d_in[6];
    const float* W1   = (const float*)d_in[7];
    const float* b1   = (const float*)d_in[8];
    const float* g1   = (const float*)d_in[9];
    const float* be1  = (const float*)d_in[10];
    const float* m1   = (const float*)d_in[11];
    const float* v1   = (const float*)d_in[12];
    const float* W2   = (const float*)d_in[13];
    const float* b2   = (const float*)d_in[14];
    const float* g2   = (const float*)d_in[15];
    const float* be2  = (const float*)d_in[16];
    const float* m2   = (const float*)d_in[17];
    const float* v2   = (const float*)d_in[18];
    const float* Wout = (const float*)d_in[19];
    const float* bout = (const float*)d_in[20];
    float* out = (float*)d_out;
    float* ws = (float*)d_ws;

    float* h0 = ws + H_OFF;
    float* h1 = ws + H_OFF + NODE_F;
    float* hA = ws + H_OFF + 2 * NODE_F;
    float* hB = ws + H_OFF + 3 * NODE_F;
    int* bh    = (int*)(ws + BH_OFF);
    int* boffs = (int*)(ws + BOFF_OFF);
    int* bcur  = (int*)(ws + BCUR_OFF);
    int* offs  = (int*)(ws + OFFS_OFF);
    int2* csr  = (int2*)(ws + CSR_OFF);
    int2* stage = (int2*)(ws + H_OFF + 2 * NODE_F);  // aliases hA/hB (pre-node_k only)

    prep_k<<<1, 256, 0, stream>>>(W1, b1, g1, be1, m1, v1, W2, b2, g2, be2, m2, v2, ws);
    embed_k<<<(NODE_F + 255) / 256, 256, 0, stream>>>(x, Win, bin, h0);

    zero_k<<<(NBK + 255) / 256, 256, 0, stream>>>(bh, NBK);
    bhist_k<<<NBLK_S, 256, 0, stream>>>(ei, bh);
    bscan_k<<<1, 1024, 0, stream>>>(bh, boffs, bcur);
    bscatter_k<<<NBLK_S, 256, 0, stream>>>(ei, eatt, bcur, stage);
    bsort2_k<<<NBK, 256, 0, stream>>>(boffs, stage, offs, csr);

    float* cur = h0;
    float* nxt = h1;
    for (int l = 0; l < L_LAYERS; ++l) {
        node_k<<<(NODE_F + 255) / 256, 256, 0, stream>>>(cur, ws, l, hA, hB);
        edge_mfma_k<<<(N_NODES + 3) / 4, 256, 0, stream>>>(offs, csr, ws, l,
                                                           cur, hA, hB, nxt);
        float* tmp = cur; cur = nxt; nxt = tmp;
    }

    head_k<<<1, 1024, 0, stream>>>(cur, cand, batch, Wout, bout, out);
}